// Round 5
// baseline (61.787 us; speedup 1.0000x reference)
//
#include <hip/hip_runtime.h>

#define NZ 2048
#define NX 2048
#define NB 4
#define ZP 2                         // z-rows per thread (register rolling)

typedef float v4f __attribute__((ext_vector_type(4)));

__device__ __forceinline__ v4f ld4(const float* p)   { return *(const v4f*)p; }
__device__ __forceinline__ void st4(float* p, v4f v) { *(v4f*)p = v; }

__global__ __launch_bounds__(256, 8) void wave_cell_kernel(
    const float* __restrict__ h1,
    const float* __restrict__ h2,
    const float* __restrict__ cl,
    const float* __restrict__ bq,
    const float* __restrict__ dtp,
    const float* __restrict__ hp,
    float* __restrict__ out)
{
    const float dt      = dtp[0];
    const float hh      = hp[0];
    const float inv_dt  = 1.0f / dt;
    const float inv_dt2 = inv_dt * inv_dt;
    const float inv_h2  = 1.0f / (hh * hh);
    const float two_inv_dt2 = 2.0f * inv_dt2;

    const int XV = NX / 4;                         // 512 float4 groups per row

    // XCD swizzle (grid=8192, %8==0 -> bijective): each XCD gets a contiguous
    // chunk of (strip-block, batch) pairs with batch varying fastest.
    int bid = blockIdx.x;
    int swz = (bid & 7) * (gridDim.x >> 3) + (bid >> 3);
    int batch = swz & (NB - 1);
    int sblk  = swz >> 2;

    int gtid  = sblk * 256 + threadIdx.x;          // within-batch thread id
    int strip = gtid >> 9;                         // /XV
    int xv    = gtid & (XV - 1);
    int x     = xv * 4;
    int z0    = strip * ZP;
    size_t base0 = (size_t)z0 * NX + x;
    const size_t plane = (size_t)NZ * NX;

    const float* p1 = h1 + (size_t)batch * plane;
    const float* p2 = h2 + (size_t)batch * plane;
    float*       oy = out + (size_t)batch * plane;
    float*       oc = out + (size_t)(NB + batch) * plane;

    const bool z_top = (z0 == 0);
    const bool z_bot = (z0 + ZP == NZ);
    const bool x_lo  = (x == 0);
    const bool x_hi  = (x + 4 == NX);

    // ---- issue all global loads up front (clamped addresses, unconditional) ----
    v4f up  = ld4(p1 + (z_top ? base0 : base0 - NX));
    v4f ctr = ld4(p1 + base0);
    v4f dn0 = ld4(p1 + base0 + NX);                           // z0+1 <= NZ-1 always
    v4f dn1 = ld4(p1 + (z_bot ? base0 : base0 + 2 * NX));

    float lft0 = p1[x_lo ? base0      : base0 - 1];
    float rgt0 = p1[x_hi ? base0      : base0 + 4];
    float lft1 = p1[x_lo ? base0 + NX : base0 + NX - 1];
    float rgt1 = p1[x_hi ? base0 + NX : base0 + NX + 4];

    v4f h2a = ld4(p2 + base0);
    v4f h2b = ld4(p2 + base0 + NX);

    v4f b0 = ld4(bq + base0);
    v4f b1 = ld4(bq + base0 + NX);
    v4f c0 = ld4(cl + base0);
    v4f c1 = ld4(cl + base0 + NX);

    if (z_top) up  = (v4f){0.f, 0.f, 0.f, 0.f};
    if (z_bot) dn1 = (v4f){0.f, 0.f, 0.f, 0.f};
    if (x_lo) { lft0 = 0.f; lft1 = 0.f; }
    if (x_hi) { rgt0 = 0.f; rgt1 = 0.f; }

    // ---- row 0 ----
    {
        v4f den = 1.0f / (inv_dt2 + b0 * inv_dt);
        v4f kk  = inv_dt2 - b0 * inv_dt;
        v4f c2  = c0 * c0 * inv_h2;
        v4f lap;
        lap.x = up.x + dn0.x + lft0  + ctr.y - 4.0f * ctr.x;
        lap.y = up.y + dn0.y + ctr.x + ctr.z - 4.0f * ctr.y;
        lap.z = up.z + dn0.z + ctr.y + ctr.w - 4.0f * ctr.z;
        lap.w = up.w + dn0.w + ctr.z + rgt0  - 4.0f * ctr.w;
        v4f yv = den * (two_inv_dt2 * ctr - kk * h2a + c2 * lap);
        st4(oy + base0, yv);
        st4(oc + base0, ctr);
    }

    // ---- row 1 (roll registers) ----
    {
        v4f den = 1.0f / (inv_dt2 + b1 * inv_dt);
        v4f kk  = inv_dt2 - b1 * inv_dt;
        v4f c2  = c1 * c1 * inv_h2;
        v4f lap;
        lap.x = ctr.x + dn1.x + lft1  + dn0.y - 4.0f * dn0.x;
        lap.y = ctr.y + dn1.y + dn0.x + dn0.z - 4.0f * dn0.y;
        lap.z = ctr.z + dn1.z + dn0.y + dn0.w - 4.0f * dn0.z;
        lap.w = ctr.w + dn1.w + dn0.z + rgt1  - 4.0f * dn0.w;
        v4f yv = den * (two_inv_dt2 * dn0 - kk * h2b + c2 * lap);
        st4(oy + base0 + NX, yv);
        st4(oc + base0 + NX, dn0);
    }
}

extern "C" void kernel_launch(void* const* d_in, const int* in_sizes, int n_in,
                              void* d_out, int out_size, void* d_ws, size_t ws_size,
                              hipStream_t stream) {
    const float* h1 = (const float*)d_in[0];
    const float* h2 = (const float*)d_in[1];
    const float* cl = (const float*)d_in[2];
    // d_in[3] = rho, unused by the reference
    const float* bq = (const float*)d_in[4];
    const float* dt = (const float*)d_in[5];
    const float* hp = (const float*)d_in[6];
    float* out = (float*)d_out;

    const int threads_per_batch = (NZ / ZP) * (NX / 4);   // 524288
    const int blocks_per_batch  = threads_per_batch / 256; // 2048
    const int grid = blocks_per_batch * NB;                // 8192, %8==0
    wave_cell_kernel<<<grid, 256, 0, stream>>>(h1, h2, cl, bq, dt, hp, out);
}

// Round 6
// 49.884 us; speedup vs baseline: 1.2386x; 1.2386x over previous
//
#include <hip/hip_runtime.h>

#define NZ 2048
#define NX 2048
#define NB 4
#define ZP 4                         // z-rows per thread (rolling 6-row window)

typedef float v4f __attribute__((ext_vector_type(4)));

__device__ __forceinline__ v4f ld4(const float* p)   { return *(const v4f*)p; }
__device__ __forceinline__ void stnt4(float* p, v4f v){ __builtin_nontemporal_store(v, (v4f*)p); }

__global__ __launch_bounds__(256, 6) void wave_cell_kernel(
    const float* __restrict__ h1,
    const float* __restrict__ h2,
    const float* __restrict__ cl,
    const float* __restrict__ bq,
    const float* __restrict__ dtp,
    const float* __restrict__ hp,
    float* __restrict__ out)
{
    const float dt      = dtp[0];
    const float hh      = hp[0];
    const float inv_dt  = 1.0f / dt;
    const float inv_dt2 = inv_dt * inv_dt;
    const float inv_h2  = 1.0f / (hh * hh);
    const float two_inv_dt2 = 2.0f * inv_dt2;

    const int XV = NX / 4;                         // 512 float4 groups per row

    // XCD swizzle (grid=4096, %8==0 -> bijective): batch varies fastest within
    // an XCD's contiguous chunk, so b/c z-bands are L2-shared across batches.
    int bid = blockIdx.x;
    int swz = (bid & 7) * (gridDim.x >> 3) + (bid >> 3);
    int batch = swz & (NB - 1);
    int sblk  = swz >> 2;

    int gtid  = sblk * 256 + threadIdx.x;          // within-batch thread id
    int strip = gtid >> 9;                         // / XV
    int xv    = gtid & (XV - 1);
    int x     = xv * 4;
    int z0    = strip * ZP;
    size_t base = (size_t)z0 * NX + x;
    const size_t plane = (size_t)NZ * NX;

    const float* p1 = h1 + (size_t)batch * plane;
    const float* p2 = h2 + (size_t)batch * plane;
    float*       oy = out + (size_t)batch * plane;
    float*       oc = out + (size_t)(NB + batch) * plane;

    const bool z_top = (z0 == 0);
    const bool z_bot = (z0 + ZP == NZ);
    const bool x_lo  = (x == 0);
    const bool x_hi  = (x + 4 == NX);

    // ---- h1 window: rows z0-1 .. z0+4 (clamped, unconditional loads) ----
    v4f a[ZP + 2];
    a[0] = ld4(p1 + (z_top ? base : base - NX));
    #pragma unroll
    for (int i = 0; i < ZP; ++i)
        a[i + 1] = ld4(p1 + base + (size_t)i * NX);
    a[ZP + 1] = ld4(p1 + (z_bot ? base : base + (size_t)ZP * NX));
    if (z_top) a[0]      = (v4f){0.f, 0.f, 0.f, 0.f};
    if (z_bot) a[ZP + 1] = (v4f){0.f, 0.f, 0.f, 0.f};

    #pragma unroll
    for (int i = 0; i < ZP; ++i) {
        const size_t rb = base + (size_t)i * NX;

        float lft = p1[x_lo ? rb : rb - 1];
        float rgt = p1[x_hi ? rb : rb + 4];
        if (x_lo) lft = 0.f;
        if (x_hi) rgt = 0.f;

        v4f h2v = ld4(p2 + rb);
        v4f bv  = ld4(bq + rb);
        v4f cv  = ld4(cl + rb);

        v4f den = 1.0f / (inv_dt2 + bv * inv_dt);
        v4f kk  = inv_dt2 - bv * inv_dt;
        v4f c2  = cv * cv * inv_h2;

        v4f up  = a[i];
        v4f ctr = a[i + 1];
        v4f dn  = a[i + 2];

        v4f lap;
        lap.x = up.x + dn.x + lft   + ctr.y - 4.0f * ctr.x;
        lap.y = up.y + dn.y + ctr.x + ctr.z - 4.0f * ctr.y;
        lap.z = up.z + dn.z + ctr.y + ctr.w - 4.0f * ctr.z;
        lap.w = up.w + dn.w + ctr.z + rgt   - 4.0f * ctr.w;

        v4f yv = den * (two_inv_dt2 * ctr - kk * h2v + c2 * lap);

        stnt4(oy + rb, yv);
        stnt4(oc + rb, ctr);       // output 1 = copy of h1
    }
}

extern "C" void kernel_launch(void* const* d_in, const int* in_sizes, int n_in,
                              void* d_out, int out_size, void* d_ws, size_t ws_size,
                              hipStream_t stream) {
    const float* h1 = (const float*)d_in[0];
    const float* h2 = (const float*)d_in[1];
    const float* cl = (const float*)d_in[2];
    // d_in[3] = rho, unused by the reference
    const float* bq = (const float*)d_in[4];
    const float* dt = (const float*)d_in[5];
    const float* hp = (const float*)d_in[6];
    float* out = (float*)d_out;

    const int threads_per_batch = (NZ / ZP) * (NX / 4);    // 262144
    const int blocks_per_batch  = threads_per_batch / 256; // 1024
    const int grid = blocks_per_batch * NB;                // 4096, %8==0
    wave_cell_kernel<<<grid, 256, 0, stream>>>(h1, h2, cl, bq, dt, hp, out);
}